// Round 12
// baseline (209.172 us; speedup 1.0000x reference)
//
#include <hip/hip_runtime.h>
#include <math.h>

// ---------------------------------------------------------------------------
// CrossViewAttention — R16: R15 + full-cover preload schedule (all B-preloads
// issued >=1 phase before use, legal across light barriers) + fattened prep
// weight-transpose (4 tiles/block) + fattened kv (A staged once per 4 B-tiles).
// 3 launches: prep -> kv -> mega(+out).
// B=1, C=256, M=4096, W=128, H=32, BLOCKS=2, HEADS=8, DH=32
// ---------------------------------------------------------------------------

#define C_DIM 256
#define M_DIM 4096
#define ATT_SCALE 0.17677669529663687f  // 1/sqrt(32)

typedef __attribute__((ext_vector_type(8))) short short8;
typedef __attribute__((ext_vector_type(4))) short short4v;
typedef __attribute__((ext_vector_type(4))) float floatx4;

__device__ __forceinline__ unsigned short f2bf(float f) {
    unsigned u = __float_as_uint(f);
    unsigned r = (u + 0x7fffu + ((u >> 16) & 1u)) >> 16;
    return (unsigned short)r;
}
__device__ __forceinline__ float gelu_exact(float x) {
    return 0.5f * x * (1.0f + erff(x * 0.70710678118654752f));
}
// LDS-only barrier: drains LDS ops then barriers; leaves global loads
// (vmcnt) in flight. Single volatile asm so the compiler cannot move any
// memory op across either side.
__device__ __forceinline__ void lbar() {
    asm volatile("s_waitcnt lgkmcnt(0)\n\ts_barrier" ::: "memory");
}

// ======================= mega prep kernel ==================================
// roles by blockIdx.x (grid 681):
//   [0,256)    transpose grd2sat -> xcur
//   [256,384)  yhat LN (bf16)
//   [384,640)  weight transpose+scale+convert, 4 tiles per block
//   [640,680)  folded biases
//   680        bucket sort
struct PrepArgs {
    const float* grd2sat; float* xcur;
    const float* grd_x;   unsigned short* yhat;   // bf16
    const float* u; int* perm; int4* chunks; int* nchunks;
    const float* win[12]; unsigned short* wout[12]; const float* wlnw[12];
    int wR[12], wC[12], wbase[13];
    const float* fW[10]; const float* flnb[10]; const float* fbase[10];
    float* fout[10];
    int fN[10], fwcol[10], focol[10];
};

__global__ __launch_bounds__(256) void prep_kernel(PrepArgs a) {
    __shared__ float smemf[9024];
    int b = blockIdx.x, t = threadIdx.x;
    if (b < 256) {
        float (*tile)[65] = (float(*)[65])smemf;
        int m0 = (b & 63) << 6, c0 = (b >> 6) << 6;
        for (int it = 0; it < 16; ++it) {
            int idx = it * 256 + t;
            int co = idx >> 6, mo = idx & 63;
            tile[co][mo] = a.grd2sat[(size_t)(c0 + co) * M_DIM + m0 + mo];
        }
        __syncthreads();
        for (int it = 0; it < 16; ++it) {
            int idx = it * 256 + t;
            int mo = idx >> 6, co = idx & 63;
            a.xcur[(size_t)(m0 + mo) * C_DIM + c0 + co] = tile[co][mo];
        }
    } else if (b < 384) {
        int idx = b - 256;
        int h = idx & 31, w0 = (idx >> 5) << 5;
        float (*tile)[33] = (float(*)[33])smemf;
        float (*ps)[32] = (float(*)[32])(smemf + 8448);
        float (*pss)[32] = (float(*)[32])(smemf + 8704);
        float* mu_s = smemf + 8960;
        float* rs_s = smemf + 8992;
        int wo = t & 31, cb = t >> 5;
        for (int it = 0; it < 32; ++it) {
            int c = it * 8 + cb;
            tile[c][wo] = a.grd_x[(size_t)c * 4096 + h * 128 + w0 + wo];
        }
        __syncthreads();
        {
            int w = t & 31, part = t >> 5;
            float s = 0.f, ss = 0.f;
            for (int c = part * 32; c < part * 32 + 32; ++c) {
                float x = tile[c][w];
                s += x; ss += x * x;
            }
            ps[part][w] = s; pss[part][w] = ss;
        }
        __syncthreads();
        if (t < 32) {
            float s = 0.f, ss = 0.f;
            for (int p = 0; p < 8; ++p) { s += ps[p][t]; ss += pss[p][t]; }
            float mu = s * (1.f / 256.f);
            float var = ss * (1.f / 256.f) - mu * mu;
            mu_s[t] = mu;
            rs_s[t] = rsqrtf(var + 1e-5f);
        }
        __syncthreads();
        for (int jj = 0; jj < 32; ++jj) {
            float mu = mu_s[jj], rs = rs_s[jj];
            a.yhat[((size_t)(w0 + jj) * 32 + h) * C_DIM + t] =
                f2bf((tile[t][jj] - mu) * rs);
        }
    } else if (b < 640) {
        float (*tile)[33] = (float(*)[33])smemf;
#pragma unroll 1
        for (int i = 0; i < 4; ++i) {
            int wI = ((b - 384) << 2) + i;
            int e = 0;
            while (wI >= a.wbase[e + 1]) ++e;
            int tl = wI - a.wbase[e];
            int tilesC = a.wC[e] >> 5;
            int tr = tl / tilesC, tc = tl - tr * tilesC;
            int r0 = tr << 5, c0 = tc << 5;
            const float* in = a.win[e];
            unsigned short* out = a.wout[e];
            const float* lnw = a.wlnw[e];
            int R = a.wR[e], Cc = a.wC[e];
            int rl = t >> 3, cq = (t & 7) << 2;
            float4 v = *(const float4*)&in[(size_t)(r0 + rl) * Cc + c0 + cq];
            if (lnw) {
                float s = lnw[r0 + rl];
                v.x *= s; v.y *= s; v.z *= s; v.w *= s;
            }
            tile[rl][cq + 0] = v.x;
            tile[rl][cq + 1] = v.y;
            tile[rl][cq + 2] = v.z;
            tile[rl][cq + 3] = v.w;
            __syncthreads();
            int cl = t >> 3, rq = (t & 7) << 2;
            ushort4 o;
            o.x = f2bf(tile[rq + 0][cl]);
            o.y = f2bf(tile[rq + 1][cl]);
            o.z = f2bf(tile[rq + 2][cl]);
            o.w = f2bf(tile[rq + 3][cl]);
            *(ushort4*)&out[(size_t)(c0 + cl) * R + r0 + rq] = o;
            __syncthreads();
        }
    } else if (b < 680) {
        int idx = b - 640;             // 0..39
        int jj = idx >> 2, part = idx & 3;
        int N = a.fN[jj];
        int c = t & 63, kp = t >> 6;   // 4 k-parts of 64
        int wcol = a.fwcol[jj] + (part << 6) + c;
        const float* W = a.fW[jj];
        const float* lb = a.flnb[jj];
        float s = 0.f;
#pragma unroll 4
        for (int k = kp * 64; k < kp * 64 + 64; ++k)
            s += lb[k] * W[(size_t)k * N + wcol];
        smemf[(kp << 6) + c] = s;
        __syncthreads();
        if (t < 64) {
            float tot = smemf[t] + smemf[64 + t] + smemf[128 + t] + smemf[192 + t];
            int ocol = a.focol[jj] + (part << 6) + t;
            if (a.fbase[jj]) tot += a.fbase[jj][a.fwcol[jj] + (part << 6) + t];
            a.fout[jj][ocol] = tot;
        }
    } else {
        int* hist = (int*)smemf;
        int* cur = (int*)smemf + 128;
        unsigned short* wlb = (unsigned short*)((int*)smemf + 256);
        if (t < 128) hist[t] = 0;
        __syncthreads();
        for (int it = 0; it < 16; ++it) {
            int m = it * 256 + t;
            int wl = (int)floorf(a.u[m]);
            wl = max(0, min(wl, 126));
            wlb[m] = (unsigned short)wl;
            atomicAdd(&hist[wl], 1);
        }
        __syncthreads();
        if (t == 0) {
            int run = 0, nc = 0;
            for (int bkt = 0; bkt < 127; ++bkt) {
                int c = hist[bkt];
                cur[bkt] = run;
                int q0 = run;
                while (c > 0) {
                    int take = min(c, 32);
                    a.chunks[nc] = make_int4(bkt, q0, take, 0);
                    ++nc; q0 += take; c -= take;
                }
                run += hist[bkt];
            }
            *a.nchunks = nc;
        }
        __syncthreads();
        for (int it = 0; it < 16; ++it) {
            int m = it * 256 + t;
            int wl = wlb[m];
            int pos = atomicAdd(&cur[wl], 1);
            a.perm[pos] = m;
        }
    }
}

// ======================= KV GEMM (A staged once per 4 B-tiles) =============
struct GJ {
    const void* A; const unsigned short* Bt;
    const float* bias;
    void* out; unsigned short* out2;
    int K, N;
};

__global__ __launch_bounds__(256) void kv_kernel(GJ j0, GJ j1) {
    __shared__ short As[32][264];
    __shared__ short Bs[64][264];
    int t = threadIdx.x;
    int bm = blockIdx.x << 5;
    int y = blockIdx.y;                 // 0..3
    const GJ& j = (y < 2) ? j0 : j1;
    int by0 = (y & 1) << 2;             // 0 or 4
    int wv = t >> 6, lane = t & 63;
    int mt = wv & 1, nt0 = (wv >> 1) << 1;
    int quad = lane >> 4, l16 = lane & 15;
    {   // A stage (32 rows x 256, bf16)
        int ar = t >> 3, cq = (t & 7) << 5;
        const unsigned short* ap =
            (const unsigned short*)j.A + (size_t)(bm + ar) * 256 + cq;
#pragma unroll
        for (int c = 0; c < 4; ++c)
            *(uint4*)&As[ar][cq + (c << 3)] = *(const uint4*)(ap + (c << 3));
    }
    __syncthreads();
#pragma unroll 1
    for (int by = by0; by < by0 + 4; ++by) {
        int bn = by << 6;
        {
            int br = t >> 2, cq2 = (t & 3) << 3;
            const unsigned short* bp = j.Bt + (size_t)(bn + br) * 256 + cq2;
#pragma unroll
            for (int g = 0; g < 8; ++g)
                *(short8*)&Bs[br][cq2 + g * 32] = *(const short8*)(bp + g * 32);
        }
        __syncthreads();
        floatx4 acc0 = {0.f, 0.f, 0.f, 0.f};
        floatx4 acc1 = {0.f, 0.f, 0.f, 0.f};
#pragma unroll
        for (int k0 = 0; k0 < 8; ++k0) {
            short8 aa = *(const short8*)&As[(mt << 4) + l16][(k0 << 5) + (quad << 3)];
            short8 b0 = *(const short8*)&Bs[(nt0 << 4) + l16][(k0 << 5) + (quad << 3)];
            short8 b1 =
                *(const short8*)&Bs[((nt0 + 1) << 4) + l16][(k0 << 5) + (quad << 3)];
            acc0 = __builtin_amdgcn_mfma_f32_16x16x32_bf16(aa, b0, acc0, 0, 0, 0);
            acc1 = __builtin_amdgcn_mfma_f32_16x16x32_bf16(aa, b1, acc1, 0, 0, 0);
        }
#pragma unroll
        for (int jj = 0; jj < 2; ++jj) {
            const floatx4 accv = jj ? acc1 : acc0;
            int col = bn + ((nt0 + jj) << 4) + l16;
            float bv = j.bias[col];
#pragma unroll
            for (int r = 0; r < 4; ++r) {
                int row = bm + (mt << 4) + (quad << 2) + r;
                float v = accv[r] + bv;
                if (col < 256)
                    ((unsigned short*)j.out)[(size_t)row * 256 + col] = f2bf(v);
                else
                    j.out2[(size_t)(col - 256) * M_DIM + row] = f2bf(v);
            }
        }
        __syncthreads();
    }
}

// ======================= mega chunk kernel v11 =============================
struct MegaArgs {
    const float* xcur;
    const int* perm; const int4* chunks; const int* nchunks;
    const unsigned short* Wq[2]; const unsigned short* Wp[2];
    const unsigned short* Wm1[2]; const unsigned short* Wm2[2];
    const unsigned short* Ktb[2]; const unsigned short* Vtb[2];
    const float* qb[2]; const float* m1b[2];
    const float* bpj[2]; const float* bm2v[2];
    const float* pw[2]; const float* pb[2];
    const float* aw; const float* ab;  // ln_post[0] for layer-1 LN2
    const float* ow; const float* ob;  // ln_post[1] for folded out
    float* oout;                        // final (C,M) output
};

struct BPre { short8 b[8][2]; };

__device__ __forceinline__ void preloadB(const unsigned short* Bt, int Kstride,
                                         int koff, int colw, int l16, int quad,
                                         BPre& P) {
    const unsigned short* bp =
        Bt + (size_t)(colw + l16) * Kstride + koff + (quad << 3);
#pragma unroll
    for (int k0 = 0; k0 < 8; ++k0)
#pragma unroll
        for (int ni = 0; ni < 2; ++ni)
            P.b[k0][ni] =
                *(const short8*)(bp + (size_t)(ni << 4) * Kstride + (k0 << 5));
}

__device__ __forceinline__ void mfma32t(const short* As, int lda, const BPre& P,
                                        int l16, int quad, floatx4 acc[2][2]) {
    const short* ap = As + (size_t)l16 * lda + (quad << 3);
#pragma unroll
    for (int k0 = 0; k0 < 8; ++k0) {
        short8 a0 = *(const short8*)(ap + (k0 << 5));
        short8 a1 = *(const short8*)(ap + (size_t)16 * lda + (k0 << 5));
        acc[0][0] = __builtin_amdgcn_mfma_f32_16x16x32_bf16(a0, P.b[k0][0], acc[0][0], 0, 0, 0);
        acc[0][1] = __builtin_amdgcn_mfma_f32_16x16x32_bf16(a0, P.b[k0][1], acc[0][1], 0, 0, 0);
        acc[1][0] = __builtin_amdgcn_mfma_f32_16x16x32_bf16(a1, P.b[k0][0], acc[1][0], 0, 0, 0);
        acc[1][1] = __builtin_amdgcn_mfma_f32_16x16x32_bf16(a1, P.b[k0][1], acc[1][1], 0, 0, 0);
    }
}

#define ZACC(A) \
    { A[0][0] = (floatx4){0.f,0.f,0.f,0.f}; A[0][1] = (floatx4){0.f,0.f,0.f,0.f}; \
      A[1][0] = (floatx4){0.f,0.f,0.f,0.f}; A[1][1] = (floatx4){0.f,0.f,0.f,0.f}; }

// LDS layout (bytes): same as R4 v4.
__global__ __launch_bounds__(512) void mega_kernel(MegaArgs a) {
    __shared__ __align__(16) char smem[137856];
    short (*XH)[264] = (short(*)[264])(smem);
    short (*QR)[264] = (short(*)[264])(smem + 16896);
    short (*ZH)[264] = (short(*)[264])(smem + 33792);
    short (*AR)[264] = (short(*)[264])(smem + 50688);
    float (*Zf)[260] = (float(*)[260])(smem + 67584);
    short (*PB)[32][72] = (short(*)[32][72])(smem + 100864);
    int* gp = (int*)(smem + 137728);

    if ((int)blockIdx.x >= *a.nchunks) return;
    int4 cd = a.chunks[blockIdx.x];
    int wl = cd.x, qstart = cd.y, qcnt = cd.z;
    int t = threadIdx.x;
    if (t < 32) gp[t] = (t < qcnt) ? a.perm[qstart + t] : a.perm[qstart];
    lbar();

    int wv = t >> 6, lane = t & 63, quad = lane >> 4, l16 = lane & 15;
    int colw = wv << 5;                     // this wave's 32-col slice
    int r16 = t >> 4, c0 = (t & 15) << 4;   // LN mapping: 16 lanes/row

#pragma unroll 1
    for (int l = 0; l < 2; ++l) {
        // ---------------- stage1: XH = LN(x) (l=1: LN->ln_post0 affine->LN)
        // Pq + attention K/V fragments issued here: full-phase(+) cover.
        BPre Pq;
        preloadB(a.Wq[l], 256, 0, colw, l16, quad, Pq);
        short8 kb[4], vfrag[2][2];
        {
            const unsigned short* Kt = a.Ktb[l];
            const unsigned short* Vt = a.Vtb[l];
            int h = wv;
#pragma unroll
            for (int nt = 0; nt < 4; ++nt)
                kb[nt] = *(const short8*)(
                    Kt + (size_t)((wl << 5) + (nt << 4) + l16) * 256 +
                    (h << 5) + (quad << 3));
#pragma unroll
            for (int ks = 0; ks < 2; ++ks)
#pragma unroll
                for (int dt = 0; dt < 2; ++dt)
                    vfrag[ks][dt] = *(const short8*)(
                        Vt + (size_t)((h << 5) + (dt << 4) + l16) * M_DIM +
                        (wl << 5) + (ks << 5) + (quad << 3));
        }
        {
            float4 v[4];
            if (l == 0) {
                const float* xp = a.xcur + (size_t)gp[r16] * 256 + c0;
#pragma unroll
                for (int g4 = 0; g4 < 4; ++g4)
                    v[g4] = *(const float4*)(xp + (g4 << 2));
            } else {
#pragma unroll
                for (int g4 = 0; g4 < 4; ++g4)
                    v[g4] = *(const float4*)&Zf[r16][c0 + (g4 << 2)];
            }
            float s = 0.f, ss = 0.f;
#pragma unroll
            for (int g4 = 0; g4 < 4; ++g4) {
                s += v[g4].x + v[g4].y + v[g4].z + v[g4].w;
                ss += v[g4].x * v[g4].x + v[g4].y * v[g4].y + v[g4].z * v[g4].z +
                      v[g4].w * v[g4].w;
            }
#pragma unroll
            for (int o = 1; o < 16; o <<= 1) {
                s += __shfl_xor(s, o, 64);
                ss += __shfl_xor(ss, o, 64);
            }
            float mu = s * (1.f / 256.f);
            float rs = rsqrtf(ss * (1.f / 256.f) - mu * mu + 1e-5f);
#pragma unroll
            for (int g4 = 0; g4 < 4; ++g4) {
                v[g4].x = (v[g4].x - mu) * rs;
                v[g4].y = (v[g4].y - mu) * rs;
                v[g4].z = (v[g4].z - mu) * rs;
                v[g4].w = (v[g4].w - mu) * rs;
            }
            if (l == 1) {
                float s2 = 0.f, ss2 = 0.f;
#pragma unroll
                for (int g4 = 0; g4 < 4; ++g4) {
                    float4 w4 = *(const float4*)&a.aw[c0 + (g4 << 2)];
                    float4 b4 = *(const float4*)&a.ab[c0 + (g4 << 2)];
                    v[g4].x = v[g4].x * w4.x + b4.x;
                    v[g4].y = v[g4].y * w4.y + b4.y;
                    v[g4].z = v[g4].z * w4.z + b4.z;
                    v[g4].w = v[g4].w * w4.w + b4.w;
                    s2 += v[g4].x + v[g4].y + v[g4].z + v[g4].w;
                    ss2 += v[g4].x * v[g4].x + v[g4].y * v[g4].y +
                           v[g4].z * v[g4].z + v[g4].w * v[g4].w;
                }
#pragma unroll
                for (int o = 1; o < 16; o <<= 1) {
                    s2 += __shfl_xor(s2, o, 64);
                    ss2 += __shfl_xor(ss2, o, 64);
                }
                float mu2 = s2 * (1.f / 256.f);
                float rs2 = rsqrtf(ss2 * (1.f / 256.f) - mu2 * mu2 + 1e-5f);
#pragma unroll
                for (int g4 = 0; g4 < 4; ++g4) {
                    v[g4].x = (v[g4].x - mu2) * rs2;
                    v[g4].y = (v[g4].y - mu2) * rs2;
                    v[g4].z = (v[g4].z - mu2) * rs2;
                    v[g4].w = (v[g4].w - mu2) * rs2;
                }
            }
#pragma unroll
            for (int g4 = 0; g4 < 4; ++g4) {
                short4v o;
                o[0] = (short)f2bf(v[g4].x);
                o[1] = (short)f2bf(v[g4].y);
                o[2] = (short)f2bf(v[g4].z);
                o[3] = (short)f2bf(v[g4].w);
                *(short4v*)&XH[r16][c0 + (g4 << 2)] = o;
            }
        }
        lbar();

        // ---------------- Q: QR = XH @ Wq'^T + qb
        {
            floatx4 acc[2][2];
            ZACC(acc);
            mfma32t((const short*)XH, 264, Pq, l16, quad, acc);
            const float* qb = a.qb[l];
#pragma unroll
            for (int ni = 0; ni < 2; ++ni) {
                int col = colw + (ni << 4) + l16;
                float bv = qb[col];
#pragma unroll
                for (int mi = 0; mi < 2; ++mi)
#pragma unroll
                    for (int r = 0; r < 4; ++r)
                        QR[(mi << 4) + (quad << 2) + r][col] =
                            (short)f2bf(acc[mi][ni][r] + bv);
            }
        }
        // wave-private QR slice: intra-wave LDS ordering only
        asm volatile("s_waitcnt lgkmcnt(0)" ::: "memory");

        // ---------------- attention: one head per wave, in-wave softmax
        // Pp issued at phase start: cover = scores + softmax + PV.
        BPre Pp;
        preloadB(a.Wp[l], 256, 0, colw, l16, quad, Pp);
        {
            int h = wv;
            short8 aq0 = *(const short8*)&QR[l16][(h << 5) + (quad << 3)];
            short8 aq1 = *(const short8*)&QR[16 + l16][(h << 5) + (quad << 3)];
            floatx4 c[2][4];
#pragma unroll
            for (int nt = 0; nt < 4; ++nt) {
                floatx4 z = {0.f, 0.f, 0.f, 0.f};
                c[0][nt] = __builtin_amdgcn_mfma_f32_16x16x32_bf16(aq0, kb[nt], z, 0, 0, 0);
                c[1][nt] = __builtin_amdgcn_mfma_f32_16x16x32_bf16(aq1, kb[nt], z, 0, 0, 0);
            }
            floatx4 ri[2];
#pragma unroll
            for (int m = 0; m < 2; ++m) {
#pragma unroll
                for (int nt = 0; nt < 4; ++nt) {
                    floatx4 e;
#pragma unroll
                    for (int r = 0; r < 4; ++r)
                        e[r] = __expf(c[m][nt][r] * ATT_SCALE);
                    c[m][nt] = e;
                }
                floatx4 s4 = c[m][0] + c[m][1] + c[m][2] + c[m][3];
#pragma unroll
                for (int r = 0; r < 4; ++r) {
                    float s = s4[r];
                    s += __shfl_xor(s, 1, 64);
                    s += __shfl_xor(s, 2, 64);
                    s += __shfl_xor(s, 4, 64);
                    s += __shfl_xor(s, 8, 64);
                    ri[m][r] = 1.f / s;
                }
            }
#pragma unroll
            for (int m = 0; m < 2; ++m)
#pragma unroll
                for (int nt = 0; nt < 4; ++nt)
#pragma unroll
                    for (int r = 0; r < 4; ++r)
                        PB[wv][(m << 4) + (quad << 2) + r][(nt << 4) + l16] =
                            (short)f2bf(c[m][nt][r] * ri[m][r]);
            asm volatile("s_waitcnt lgkmcnt(0)" ::: "memory");
            floatx4 o[2][2];
#pragma unroll
            for (int m = 0; m < 2; ++m)
#pragma unroll
                for (int dt = 0; dt < 2; ++dt)
                    o[m][dt] = (floatx4){0.f, 0.f, 0.f, 0.f};
#pragma unroll
            for (int ks = 0; ks < 2; ++ks) {
                short8 pa0 =
                    *(const short8*)&PB[wv][l16][(ks << 5) + (quad << 3)];
                short8 pa1 =
                    *(const short8*)&PB[wv][16 + l16][(ks << 5) + (quad << 3)];
#pragma unroll
                for (int dt = 0; dt < 2; ++dt) {
                    o[0][dt] = __builtin_amdgcn_mfma_f32_16x16x32_bf16(
                        pa0, vfrag[ks][dt], o[0][dt], 0, 0, 0);
                    o[1][dt] = __builtin_amdgcn_mfma_f32_16x16x32_bf16(
                        pa1, vfrag[ks][dt], o[1][dt], 0, 0, 0);
                }
            }
            int h5 = wv << 5;
#pragma unroll
            for (int m = 0; m < 2; ++m)
#pragma unroll
                for (int dt = 0; dt < 2; ++dt)
#pragma unroll
                    for (int r = 0; r < 4; ++r)
                        AR[(m << 4) + (quad << 2) + r]
                          [h5 + (dt << 4) + l16] = (short)f2bf(o[m][dt][r]);
        }
        lbar();

        // ---------------- proj: Zf = AR @ Wp'^T + bproj (fp32)
        {
            floatx4 acc[2][2];
            ZACC(acc);
            mfma32t((const short*)AR, 264, Pp, l16, quad, acc);
            const float* bpj = a.bpj[l];
#pragma unroll
            for (int ni = 0; ni < 2; ++ni) {
                int col = colw + (ni << 4) + l16;
                float bv = bpj[col];
#pragma unroll
                for (int mi = 0; mi < 2; ++mi)
#pragma unroll
                    for (int r = 0; r < 4; ++r)
                        Zf[(mi << 4) + (quad << 2) + r][col] = acc[mi][ni][r] + bv;
            }
        }
        lbar();

        // ---------------- LNz: ZH = bf16(LN(Z)); Zf <- LN(Z)*pw+pb
        // Pm1a AND Pm1b issued here: both get full LNz-phase cover.
        BPre Pm1a, Pm1b;
        preloadB(a.Wm1[l], 256, 0, colw, l16, quad, Pm1a);
        preloadB(a.Wm1[l] + (size_t)256 * 256, 256, 0, colw, l16, quad, Pm1b);
        {
            const float* pw = a.pw[l];
            const float* pb = a.pb[l];
            float4 v[4];
#pragma unroll
            for (int g4 = 0; g4 < 4; ++g4)
                v[g4] = *(const float4*)&Zf[r16][c0 + (g4 << 2)];
            float s = 0.f, ss = 0.f;
#pragma unroll
            for (int g4 = 0; g4 < 4; ++g4) {
                s += v[g4].x + v[g4].y + v[g4].z + v[g4].w;
                ss += v[g4].x * v[g4].x + v[g4].y * v[g4].y + v[g4].z * v[g4].z +
                      v[g4].w * v[g4].w;
            }
#pragma unroll
            for (int o = 1; o < 16; o <<= 1) {
                s += __shfl_xor(s, o, 64);
                ss += __shfl_xor(ss, o, 64);
            }
            float mu = s * (1.f / 256.f);
            float rs = rsqrtf(ss * (1.f / 256.f) - mu * mu + 1e-5f);
#pragma unroll
            for (int g4 = 0; g4 < 4; ++g4) {
                float4 z;
                z.x = (v[g4].x - mu) * rs;
                z.y = (v[g4].y - mu) * rs;
                z.z = (v[g4].z - mu) * rs;
                z.w = (v[g4].w - mu) * rs;
                short4v o;
                o[0] = (short)f2bf(z.x);
                o[1] = (short)f2bf(z.y);
                o[2] = (short)f2bf(z.z);
                o[3] = (short)f2bf(z.w);
                *(short4v*)&ZH[r16][c0 + (g4 << 2)] = o;
                float4 w4 = *(const float4*)&pw[c0 + (g4 << 2)];
                float4 b4 = *(const float4*)&pb[c0 + (g4 << 2)];
                float4 za;
                za.x = z.x * w4.x + b4.x;
                za.y = z.y * w4.y + b4.y;
                za.z = z.z * w4.z + b4.z;
                za.w = z.w * w4.w + b4.w;
                *(float4*)&Zf[r16][c0 + (g4 << 2)] = za;
            }
        }
        lbar();

        // ---------------- m1: gelu(ZH @ Wm1'^T + m1b) -> HH0(XH), HH1(QR)
        // Pm2a issued after first MFMA block (Pm1a dead), Pm2b after second.
        const float* m1b = a.m1b[l];
        BPre Pm2a, Pm2b;
        {
            floatx4 acc[2][2];
            ZACC(acc);
            mfma32t((const short*)ZH, 264, Pm1a, l16, quad, acc);
            preloadB(a.Wm2[l], 512, 0, colw, l16, quad, Pm2a);
#pragma unroll
            for (int ni = 0; ni < 2; ++ni) {
                int col = colw + (ni << 4) + l16;
                float bv = m1b[col];
#pragma unroll
                for (int mi = 0; mi < 2; ++mi)
#pragma unroll
                    for (int r = 0; r < 4; ++r)
                        XH[(mi << 4) + (quad << 2) + r][col] =
                            (short)f2bf(gelu_exact(acc[mi][ni][r] + bv));
            }
            floatx4 acc2[2][2];
            ZACC(acc2);
            mfma32t((const short*)ZH, 264, Pm1b, l16, quad, acc2);
            preloadB(a.Wm2[l], 512, 256, colw, l16, quad, Pm2b);
#pragma unroll
            for (int ni = 0; ni < 2; ++ni) {
                int col = colw + (ni << 4) + l16;
                float bv = m1b[256 + col];
#pragma unroll
                for (int mi = 0; mi < 2; ++mi)
#pragma unroll
                    for (int r = 0; r < 4; ++r)
                        QR[(mi << 4) + (quad << 2) + r][col] =
                            (short)f2bf(gelu_exact(acc2[mi][ni][r] + bv));
            }
        }
        lbar();

        // ---------------- m2: x' = HH @ Wm2'^T + bm2 + Zf (K=512)
        {
            floatx4 macc[2][2];
            ZACC(macc);
            mfma32t((const short*)XH, 264, Pm2a, l16, quad, macc);
            mfma32t((const short*)QR, 264, Pm2b, l16, quad, macc);
            const float* b2 = a.bm2v[l];
#pragma unroll
            for (int ni = 0; ni < 2; ++ni) {
                int col = colw + (ni << 4) + l16;
                float bv = b2[col];
#pragma unroll
                for (int mi = 0; mi < 2; ++mi)
#pragma unroll
                    for (int r = 0; r < 4; ++r) {
                        int row = (mi << 4) + (quad << 2) + r;
                        Zf[row][col] = macc[mi][ni][r] + bv + Zf[row][col];
                    }
            }
        }
        lbar();
    }

    // ---------------- folded out: LN_post1 + channel-L2-norm + store -------
    {
        float4 v[4];
#pragma unroll
        for (int g4 = 0; g4 < 4; ++g4)
            v[g4] = *(const float4*)&Zf[r16][c0 + (g4 << 2)];
        float s = 0.f, ss = 0.f;
#pragma unroll
        for (int g4 = 0; g4 < 4; ++g4) {
            s += v[g4].x + v[g4].y + v[g4].z + v[g4].w;
            ss += v[g4].x * v[g4].x + v[g4].y * v[g4].y + v[g4].z * v[g4].z +
                  v[g4].w * v[g4].w;
        }
#pragma unroll
        for (int o = 1; o < 16; o <<= 1) {
            s += __shfl_xor(s, o, 64);
            ss += __shfl_xor(ss, o, 64);
        }
        float mu = s * (1.f / 256.f);
        float rs = rsqrtf(ss * (1.f / 256.f) - mu * mu + 1e-5f);
        float ss2 = 0.f;
#pragma unroll
        for (int g4 = 0; g4 < 4; ++g4) {
            float4 w4 = *(const float4*)&a.ow[c0 + (g4 << 2)];
            float4 b4 = *(const float4*)&a.ob[c0 + (g4 << 2)];
            v[g4].x = (v[g4].x - mu) * rs * w4.x + b4.x;
            v[g4].y = (v[g4].y - mu) * rs * w4.y + b4.y;
            v[g4].z = (v[g4].z - mu) * rs * w4.z + b4.z;
            v[g4].w = (v[g4].w - mu) * rs * w4.w + b4.w;
            ss2 += v[g4].x * v[g4].x + v[g4].y * v[g4].y + v[g4].z * v[g4].z +
                   v[g4].w * v[g4].w;
        }
#pragma unroll
        for (int o = 1; o < 16; o <<= 1) ss2 += __shfl_xor(ss2, o, 64);
        float sc = 1.f / fmaxf(sqrtf(ss2), 1e-12f);
        if (r16 < qcnt) {
            int m = gp[r16];
            float* op = a.oout + m;
#pragma unroll
            for (int g4 = 0; g4 < 4; ++g4) {
                int cb = c0 + (g4 << 2);
                op[(size_t)(cb + 0) * M_DIM] = v[g4].x * sc;
                op[(size_t)(cb + 1) * M_DIM] = v[g4].y * sc;
                op[(size_t)(cb + 2) * M_DIM] = v[g4].z * sc;
                op[(size_t)(cb + 3) * M_DIM] = v[g4].w * sc;
            }
        }
    }
}

// ---------------------------------------------------------------------------
extern "C" void kernel_launch(void* const* d_in, const int* in_sizes, int n_in,
                              void* d_out, int out_size, void* d_ws, size_t ws_size,
                              hipStream_t stream) {
    const float* grd2sat = (const float*)d_in[0];
    const float* grd_x   = (const float*)d_in[1];
    const float* u       = (const float*)d_in[2];
    const float* ln_q_w  = (const float*)d_in[3];
    const float* ln_q_b  = (const float*)d_in[4];
    const float* ln_k_w  = (const float*)d_in[5];
    const float* ln_k_b  = (const float*)d_in[6];
    const float* ln_v_w  = (const float*)d_in[7];
    const float* ln_v_b  = (const float*)d_in[8];
    const float* Wq      = (const float*)d_in[9];
    const float* Wk      = (const float*)d_in[10];
    const float* Wv      = (const float*)d_in[11];
    const float* Wproj   = (const float*)d_in[12];
    const float* bproj   = (const float*)d_in[13];
    const float* ln_pre_w = (const float*)d_in[14];
    const float* ln_pre_b = (const float*)d_in[15];
    const float* Wm1     = (const float*)d_in[16];
    const float* bm1     = (const float*)d_in[17];
    const float* Wm2     = (const float*)d_in[18];
    const float* bm2     = (const float*)d_in[19];
    const float* ln_post_w = (const float*)d_in[20];
    const float* ln_post_b = (const float*)d_in[21];

    float* ws   = (float*)d_ws;
    unsigned short* yhat = (unsigned short*)ws;  // 2 MB bf16
    float* xcur = ws + 1048576;              // 4 MB
    unsigned short* Ktab0 = (unsigned short*)(ws + 6291456); // 2 MB
    unsigned short* Vt0   = (unsigned short*)(ws + 6815744); // 2 MB
    unsigned short* Ktab1 = (unsigned short*)(ws + 7340032); // 2 MB
    unsigned short* Vt1   = (unsigned short*)(ws + 7864320); // 2 MB
    unsigned short* Bt    = (unsigned short*)(ws + 8388608); // 2 MB
    float* biasbuf = ws + 8912896;           // 2560 floats
    int*  perm    = (int*)(ws + 8915456);
    int4* chunks  = (int4*)(ws + 8919552);
    int*  nchunks = (int*)(ws + 8921600);
    const size_t BS = 524288;
    const size_t OQ = 0, OKV = 65536, OP = 196608, OM1 = 262144, OM2 = 393216;

    dim3 b256(256);

    PrepArgs pa;
    pa.grd2sat = grd2sat; pa.xcur = xcur;
    pa.grd_x = grd_x;     pa.yhat = yhat;
    pa.u = u; pa.perm = perm; pa.chunks = chunks; pa.nchunks = nchunks;
    {
        int base = 0;
        for (int i = 0; i < 2; ++i) {
            int e = 6 * i;
            unsigned short* bt = Bt + i * BS;
            pa.win[e+0] = Wq + i * 65536;    pa.wout[e+0] = bt + OQ;
            pa.wlnw[e+0] = ln_q_w + i * 256; pa.wR[e+0] = 256; pa.wC[e+0] = 256;
            pa.win[e+1] = Wk + i * 65536;    pa.wout[e+1] = bt + OKV;
            pa.wlnw[e+1] = ln_k_w + i * 256; pa.wR[e+1] = 256; pa.wC[e+1] = 256;
            pa.win[e+2] = Wv + i * 65536;    pa.wout[e+2] = bt + OKV + 65536;
            pa.wlnw[e+2] = ln_v_w + i * 256; pa.wR[e+2] = 256; pa.wC[e+2] = 256;
            pa.win[e+3] = Wproj + i * 65536; pa.wout[e+3] = bt + OP;
            pa.wlnw[e+3] = nullptr;          pa.wR[e+3] = 256; pa.wC[e+3] = 256;
            pa.win[e+4] = Wm1 + i * 131072;  pa.wout[e+4] = bt + OM1;
            pa.wlnw[e+4] = ln_pre_w + i * 256; pa.wR[e+4] = 256; pa.wC[e+4] = 512;
            pa.win[e+5] = Wm2 + i * 131072;  pa.wout[e+5] = bt + OM2;
            pa.wlnw[e+5] = nullptr;          pa.wR[e+5] = 512; pa.wC[e+5] = 256;
        }
        for (int e = 0; e < 12; ++e) {
            pa.wbase[e] = base;
            base += (pa.wR[e] >> 5) * (pa.wC[e] >> 5);
        }
        pa.wbase[12] = base;  // 1024
        for (int i = 0; i < 2; ++i) {
            int jb = 5 * i;
            float* bb = biasbuf + i * 1280;
            pa.fW[jb+0] = Wq + i * 65536; pa.flnb[jb+0] = ln_q_b + i * 256;
            pa.fbase[jb+0] = nullptr; pa.fout[jb+0] = bb;
            pa.fN[jb+0] = 256; pa.fwcol[jb+0] = 0; pa.focol[jb+0] = 0;
            pa.fW[jb+1] = Wk + i * 65536; pa.flnb[jb+1] = ln_k_b + i * 256;
            pa.fbase[jb+1] = nullptr; pa.fout[jb+1] = bb + 256;
            pa.fN[jb+1] = 256; pa.fwcol[jb+1] = 0; pa.focol[jb+1] = 0;
            pa.fW[jb+2] = Wv + i * 65536; pa.flnb[jb+2] = ln_v_b + i * 256;
            pa.fbase[jb+2] = nullptr; pa.fout[jb+2] = bb + 256;
            pa.fN[jb+2] = 256; pa.fwcol[jb+2] = 0; pa.focol[jb+2] = 256;
            pa.fW[jb+3] = Wm1 + i * 131072; pa.flnb[jb+3] = ln_pre_b + i * 256;
            pa.fbase[jb+3] = bm1 + i * 512; pa.fout[jb+3] = bb + 768;
            pa.fN[jb+3] = 512; pa.fwcol[jb+3] = 0; pa.focol[jb+3] = 0;
            pa.fW[jb+4] = Wm1 + i * 131072; pa.flnb[jb+4] = ln_pre_b + i * 256;
            pa.fbase[jb+4] = bm1 + i * 512; pa.fout[jb+4] = bb + 768;
            pa.fN[jb+4] = 512; pa.fwcol[jb+4] = 256; pa.focol[jb+4] = 256;
        }
    }
    prep_kernel<<<681, b256, 0, stream>>>(pa);

    // ---- K/V tables for both transformer blocks
    GJ jkv0 = {};
    jkv0.A = yhat; jkv0.Bt = Bt + OKV; jkv0.bias = biasbuf + 256;
    jkv0.out = Ktab0; jkv0.out2 = Vt0; jkv0.K = 256; jkv0.N = 512;
    GJ jkv1 = {};
    jkv1.A = yhat; jkv1.Bt = Bt + BS + OKV; jkv1.bias = biasbuf + 1280 + 256;
    jkv1.out = Ktab1; jkv1.out2 = Vt1; jkv1.K = 256; jkv1.N = 512;
    kv_kernel<<<dim3(128, 4), b256, 0, stream>>>(jkv0, jkv1);

    // ---- mega chunk kernel v11 (full-cover preload schedule)
    MegaArgs ma;
    ma.xcur = xcur; ma.perm = perm; ma.chunks = chunks; ma.nchunks = nchunks;
    for (int i = 0; i < 2; ++i) {
        const unsigned short* bt = Bt + i * BS;
        ma.Wq[i] = bt + OQ; ma.Wp[i] = bt + OP;
        ma.Wm1[i] = bt + OM1; ma.Wm2[i] = bt + OM2;
        ma.Ktb[i] = i ? Ktab1 : Ktab0; ma.Vtb[i] = i ? Vt1 : Vt0;
        ma.qb[i] = biasbuf + i * 1280;
        ma.m1b[i] = biasbuf + i * 1280 + 768;
        ma.bpj[i] = bproj + i * 256;
        ma.bm2v[i] = bm2 + i * 256;
        ma.pw[i] = ln_pre_w + i * 256;
        ma.pb[i] = ln_pre_b + i * 256;
    }
    ma.aw = ln_post_w; ma.ab = ln_post_b;         // block-0 ln_post (LN2)
    ma.ow = ln_post_w + 256; ma.ob = ln_post_b + 256;  // block-1 ln_post (out)
    ma.oout = (float*)d_out;
    mega_kernel<<<288, dim3(512), 0, stream>>>(ma);
}

// Round 13
// 200.845 us; speedup vs baseline: 1.0415x; 1.0415x over previous
//
#include <hip/hip_runtime.h>
#include <math.h>

// ---------------------------------------------------------------------------
// CrossViewAttention — R17: best-known config. R15 mega (R4 preload placement
// + LDS-only light barriers, VGPR 108, no spill) + R16 fattened prep/kv.
// 3 launches: prep -> kv -> mega(+out).
// B=1, C=256, M=4096, W=128, H=32, BLOCKS=2, HEADS=8, DH=32
// ---------------------------------------------------------------------------

#define C_DIM 256
#define M_DIM 4096
#define ATT_SCALE 0.17677669529663687f  // 1/sqrt(32)

typedef __attribute__((ext_vector_type(8))) short short8;
typedef __attribute__((ext_vector_type(4))) short short4v;
typedef __attribute__((ext_vector_type(4))) float floatx4;

__device__ __forceinline__ unsigned short f2bf(float f) {
    unsigned u = __float_as_uint(f);
    unsigned r = (u + 0x7fffu + ((u >> 16) & 1u)) >> 16;
    return (unsigned short)r;
}
__device__ __forceinline__ float gelu_exact(float x) {
    return 0.5f * x * (1.0f + erff(x * 0.70710678118654752f));
}
// LDS-only barrier: drains LDS ops then barriers; leaves global loads
// (vmcnt) in flight. Single volatile asm so the compiler cannot move any
// memory op across either side.
__device__ __forceinline__ void lbar() {
    asm volatile("s_waitcnt lgkmcnt(0)\n\ts_barrier" ::: "memory");
}

// ======================= mega prep kernel ==================================
// roles by blockIdx.x (grid 681):
//   [0,256)    transpose grd2sat -> xcur
//   [256,384)  yhat LN (bf16)
//   [384,640)  weight transpose+scale+convert, 4 tiles per block
//   [640,680)  folded biases
//   680        bucket sort
struct PrepArgs {
    const float* grd2sat; float* xcur;
    const float* grd_x;   unsigned short* yhat;   // bf16
    const float* u; int* perm; int4* chunks; int* nchunks;
    const float* win[12]; unsigned short* wout[12]; const float* wlnw[12];
    int wR[12], wC[12], wbase[13];
    const float* fW[10]; const float* flnb[10]; const float* fbase[10];
    float* fout[10];
    int fN[10], fwcol[10], focol[10];
};

__global__ __launch_bounds__(256) void prep_kernel(PrepArgs a) {
    __shared__ float smemf[9024];
    int b = blockIdx.x, t = threadIdx.x;
    if (b < 256) {
        float (*tile)[65] = (float(*)[65])smemf;
        int m0 = (b & 63) << 6, c0 = (b >> 6) << 6;
        for (int it = 0; it < 16; ++it) {
            int idx = it * 256 + t;
            int co = idx >> 6, mo = idx & 63;
            tile[co][mo] = a.grd2sat[(size_t)(c0 + co) * M_DIM + m0 + mo];
        }
        __syncthreads();
        for (int it = 0; it < 16; ++it) {
            int idx = it * 256 + t;
            int mo = idx >> 6, co = idx & 63;
            a.xcur[(size_t)(m0 + mo) * C_DIM + c0 + co] = tile[co][mo];
        }
    } else if (b < 384) {
        int idx = b - 256;
        int h = idx & 31, w0 = (idx >> 5) << 5;
        float (*tile)[33] = (float(*)[33])smemf;
        float (*ps)[32] = (float(*)[32])(smemf + 8448);
        float (*pss)[32] = (float(*)[32])(smemf + 8704);
        float* mu_s = smemf + 8960;
        float* rs_s = smemf + 8992;
        int wo = t & 31, cb = t >> 5;
        for (int it = 0; it < 32; ++it) {
            int c = it * 8 + cb;
            tile[c][wo] = a.grd_x[(size_t)c * 4096 + h * 128 + w0 + wo];
        }
        __syncthreads();
        {
            int w = t & 31, part = t >> 5;
            float s = 0.f, ss = 0.f;
            for (int c = part * 32; c < part * 32 + 32; ++c) {
                float x = tile[c][w];
                s += x; ss += x * x;
            }
            ps[part][w] = s; pss[part][w] = ss;
        }
        __syncthreads();
        if (t < 32) {
            float s = 0.f, ss = 0.f;
            for (int p = 0; p < 8; ++p) { s += ps[p][t]; ss += pss[p][t]; }
            float mu = s * (1.f / 256.f);
            float var = ss * (1.f / 256.f) - mu * mu;
            mu_s[t] = mu;
            rs_s[t] = rsqrtf(var + 1e-5f);
        }
        __syncthreads();
        for (int jj = 0; jj < 32; ++jj) {
            float mu = mu_s[jj], rs = rs_s[jj];
            a.yhat[((size_t)(w0 + jj) * 32 + h) * C_DIM + t] =
                f2bf((tile[t][jj] - mu) * rs);
        }
    } else if (b < 640) {
        float (*tile)[33] = (float(*)[33])smemf;
#pragma unroll 1
        for (int i = 0; i < 4; ++i) {
            int wI = ((b - 384) << 2) + i;
            int e = 0;
            while (wI >= a.wbase[e + 1]) ++e;
            int tl = wI - a.wbase[e];
            int tilesC = a.wC[e] >> 5;
            int tr = tl / tilesC, tc = tl - tr * tilesC;
            int r0 = tr << 5, c0 = tc << 5;
            const float* in = a.win[e];
            unsigned short* out = a.wout[e];
            const float* lnw = a.wlnw[e];
            int R = a.wR[e], Cc = a.wC[e];
            int rl = t >> 3, cq = (t & 7) << 2;
            float4 v = *(const float4*)&in[(size_t)(r0 + rl) * Cc + c0 + cq];
            if (lnw) {
                float s = lnw[r0 + rl];
                v.x *= s; v.y *= s; v.z *= s; v.w *= s;
            }
            tile[rl][cq + 0] = v.x;
            tile[rl][cq + 1] = v.y;
            tile[rl][cq + 2] = v.z;
            tile[rl][cq + 3] = v.w;
            __syncthreads();
            int cl = t >> 3, rq = (t & 7) << 2;
            ushort4 o;
            o.x = f2bf(tile[rq + 0][cl]);
            o.y = f2bf(tile[rq + 1][cl]);
            o.z = f2bf(tile[rq + 2][cl]);
            o.w = f2bf(tile[rq + 3][cl]);
            *(ushort4*)&out[(size_t)(c0 + cl) * R + r0 + rq] = o;
            __syncthreads();
        }
    } else if (b < 680) {
        int idx = b - 640;             // 0..39
        int jj = idx >> 2, part = idx & 3;
        int N = a.fN[jj];
        int c = t & 63, kp = t >> 6;   // 4 k-parts of 64
        int wcol = a.fwcol[jj] + (part << 6) + c;
        const float* W = a.fW[jj];
        const float* lb = a.flnb[jj];
        float s = 0.f;
#pragma unroll 4
        for (int k = kp * 64; k < kp * 64 + 64; ++k)
            s += lb[k] * W[(size_t)k * N + wcol];
        smemf[(kp << 6) + c] = s;
        __syncthreads();
        if (t < 64) {
            float tot = smemf[t] + smemf[64 + t] + smemf[128 + t] + smemf[192 + t];
            int ocol = a.focol[jj] + (part << 6) + t;
            if (a.fbase[jj]) tot += a.fbase[jj][a.fwcol[jj] + (part << 6) + t];
            a.fout[jj][ocol] = tot;
        }
    } else {
        int* hist = (int*)smemf;
        int* cur = (int*)smemf + 128;
        unsigned short* wlb = (unsigned short*)((int*)smemf + 256);
        if (t < 128) hist[t] = 0;
        __syncthreads();
        for (int it = 0; it < 16; ++it) {
            int m = it * 256 + t;
            int wl = (int)floorf(a.u[m]);
            wl = max(0, min(wl, 126));
            wlb[m] = (unsigned short)wl;
            atomicAdd(&hist[wl], 1);
        }
        __syncthreads();
        if (t == 0) {
            int run = 0, nc = 0;
            for (int bkt = 0; bkt < 127; ++bkt) {
                int c = hist[bkt];
                cur[bkt] = run;
                int q0 = run;
                while (c > 0) {
                    int take = min(c, 32);
                    a.chunks[nc] = make_int4(bkt, q0, take, 0);
                    ++nc; q0 += take; c -= take;
                }
                run += hist[bkt];
            }
            *a.nchunks = nc;
        }
        __syncthreads();
        for (int it = 0; it < 16; ++it) {
            int m = it * 256 + t;
            int wl = wlb[m];
            int pos = atomicAdd(&cur[wl], 1);
            a.perm[pos] = m;
        }
    }
}

// ======================= KV GEMM (A staged once per 4 B-tiles) =============
struct GJ {
    const void* A; const unsigned short* Bt;
    const float* bias;
    void* out; unsigned short* out2;
    int K, N;
};

__global__ __launch_bounds__(256) void kv_kernel(GJ j0, GJ j1) {
    __shared__ short As[32][264];
    __shared__ short Bs[64][264];
    int t = threadIdx.x;
    int bm = blockIdx.x << 5;
    int y = blockIdx.y;                 // 0..3
    const GJ& j = (y < 2) ? j0 : j1;
    int by0 = (y & 1) << 2;             // 0 or 4
    int wv = t >> 6, lane = t & 63;
    int mt = wv & 1, nt0 = (wv >> 1) << 1;
    int quad = lane >> 4, l16 = lane & 15;
    {   // A stage (32 rows x 256, bf16)
        int ar = t >> 3, cq = (t & 7) << 5;
        const unsigned short* ap =
            (const unsigned short*)j.A + (size_t)(bm + ar) * 256 + cq;
#pragma unroll
        for (int c = 0; c < 4; ++c)
            *(uint4*)&As[ar][cq + (c << 3)] = *(const uint4*)(ap + (c << 3));
    }
    __syncthreads();
#pragma unroll 1
    for (int by = by0; by < by0 + 4; ++by) {
        int bn = by << 6;
        {
            int br = t >> 2, cq2 = (t & 3) << 3;
            const unsigned short* bp = j.Bt + (size_t)(bn + br) * 256 + cq2;
#pragma unroll
            for (int g = 0; g < 8; ++g)
                *(short8*)&Bs[br][cq2 + g * 32] = *(const short8*)(bp + g * 32);
        }
        __syncthreads();
        floatx4 acc0 = {0.f, 0.f, 0.f, 0.f};
        floatx4 acc1 = {0.f, 0.f, 0.f, 0.f};
#pragma unroll
        for (int k0 = 0; k0 < 8; ++k0) {
            short8 aa = *(const short8*)&As[(mt << 4) + l16][(k0 << 5) + (quad << 3)];
            short8 b0 = *(const short8*)&Bs[(nt0 << 4) + l16][(k0 << 5) + (quad << 3)];
            short8 b1 =
                *(const short8*)&Bs[((nt0 + 1) << 4) + l16][(k0 << 5) + (quad << 3)];
            acc0 = __builtin_amdgcn_mfma_f32_16x16x32_bf16(aa, b0, acc0, 0, 0, 0);
            acc1 = __builtin_amdgcn_mfma_f32_16x16x32_bf16(aa, b1, acc1, 0, 0, 0);
        }
#pragma unroll
        for (int jj = 0; jj < 2; ++jj) {
            const floatx4 accv = jj ? acc1 : acc0;
            int col = bn + ((nt0 + jj) << 4) + l16;
            float bv = j.bias[col];
#pragma unroll
            for (int r = 0; r < 4; ++r) {
                int row = bm + (mt << 4) + (quad << 2) + r;
                float v = accv[r] + bv;
                if (col < 256)
                    ((unsigned short*)j.out)[(size_t)row * 256 + col] = f2bf(v);
                else
                    j.out2[(size_t)(col - 256) * M_DIM + row] = f2bf(v);
            }
        }
        __syncthreads();
    }
}

// ======================= mega chunk kernel v12 (R15-exact) =================
struct MegaArgs {
    const float* xcur;
    const int* perm; const int4* chunks; const int* nchunks;
    const unsigned short* Wq[2]; const unsigned short* Wp[2];
    const unsigned short* Wm1[2]; const unsigned short* Wm2[2];
    const unsigned short* Ktb[2]; const unsigned short* Vtb[2];
    const float* qb[2]; const float* m1b[2];
    const float* bpj[2]; const float* bm2v[2];
    const float* pw[2]; const float* pb[2];
    const float* aw; const float* ab;  // ln_post[0] for layer-1 LN2
    const float* ow; const float* ob;  // ln_post[1] for folded out
    float* oout;                        // final (C,M) output
};

struct BPre { short8 b[8][2]; };

__device__ __forceinline__ void preloadB(const unsigned short* Bt, int Kstride,
                                         int koff, int colw, int l16, int quad,
                                         BPre& P) {
    const unsigned short* bp =
        Bt + (size_t)(colw + l16) * Kstride + koff + (quad << 3);
#pragma unroll
    for (int k0 = 0; k0 < 8; ++k0)
#pragma unroll
        for (int ni = 0; ni < 2; ++ni)
            P.b[k0][ni] =
                *(const short8*)(bp + (size_t)(ni << 4) * Kstride + (k0 << 5));
}

__device__ __forceinline__ void mfma32t(const short* As, int lda, const BPre& P,
                                        int l16, int quad, floatx4 acc[2][2]) {
    const short* ap = As + (size_t)l16 * lda + (quad << 3);
#pragma unroll
    for (int k0 = 0; k0 < 8; ++k0) {
        short8 a0 = *(const short8*)(ap + (k0 << 5));
        short8 a1 = *(const short8*)(ap + (size_t)16 * lda + (k0 << 5));
        acc[0][0] = __builtin_amdgcn_mfma_f32_16x16x32_bf16(a0, P.b[k0][0], acc[0][0], 0, 0, 0);
        acc[0][1] = __builtin_amdgcn_mfma_f32_16x16x32_bf16(a0, P.b[k0][1], acc[0][1], 0, 0, 0);
        acc[1][0] = __builtin_amdgcn_mfma_f32_16x16x32_bf16(a1, P.b[k0][0], acc[1][0], 0, 0, 0);
        acc[1][1] = __builtin_amdgcn_mfma_f32_16x16x32_bf16(a1, P.b[k0][1], acc[1][1], 0, 0, 0);
    }
}

#define ZACC(A) \
    { A[0][0] = (floatx4){0.f,0.f,0.f,0.f}; A[0][1] = (floatx4){0.f,0.f,0.f,0.f}; \
      A[1][0] = (floatx4){0.f,0.f,0.f,0.f}; A[1][1] = (floatx4){0.f,0.f,0.f,0.f}; }

// LDS layout (bytes): same as R4 v4.
__global__ __launch_bounds__(512) void mega_kernel(MegaArgs a) {
    __shared__ __align__(16) char smem[137856];
    short (*XH)[264] = (short(*)[264])(smem);
    short (*QR)[264] = (short(*)[264])(smem + 16896);
    short (*ZH)[264] = (short(*)[264])(smem + 33792);
    short (*AR)[264] = (short(*)[264])(smem + 50688);
    float (*Zf)[260] = (float(*)[260])(smem + 67584);
    short (*PB)[32][72] = (short(*)[32][72])(smem + 100864);
    int* gp = (int*)(smem + 137728);

    if ((int)blockIdx.x >= *a.nchunks) return;
    int4 cd = a.chunks[blockIdx.x];
    int wl = cd.x, qstart = cd.y, qcnt = cd.z;
    int t = threadIdx.x;
    if (t < 32) gp[t] = (t < qcnt) ? a.perm[qstart + t] : a.perm[qstart];
    lbar();

    int wv = t >> 6, lane = t & 63, quad = lane >> 4, l16 = lane & 15;
    int colw = wv << 5;                     // this wave's 32-col slice
    int r16 = t >> 4, c0 = (t & 15) << 4;   // LN mapping: 16 lanes/row

#pragma unroll 1
    for (int l = 0; l < 2; ++l) {
        // ---------------- stage1: XH = LN(x) (l=1: LN->ln_post0 affine->LN)
        BPre Pq;
        preloadB(a.Wq[l], 256, 0, colw, l16, quad, Pq);  // stays in flight
        {
            float4 v[4];
            if (l == 0) {
                const float* xp = a.xcur + (size_t)gp[r16] * 256 + c0;
#pragma unroll
                for (int g4 = 0; g4 < 4; ++g4)
                    v[g4] = *(const float4*)(xp + (g4 << 2));
            } else {
#pragma unroll
                for (int g4 = 0; g4 < 4; ++g4)
                    v[g4] = *(const float4*)&Zf[r16][c0 + (g4 << 2)];
            }
            float s = 0.f, ss = 0.f;
#pragma unroll
            for (int g4 = 0; g4 < 4; ++g4) {
                s += v[g4].x + v[g4].y + v[g4].z + v[g4].w;
                ss += v[g4].x * v[g4].x + v[g4].y * v[g4].y + v[g4].z * v[g4].z +
                      v[g4].w * v[g4].w;
            }
#pragma unroll
            for (int o = 1; o < 16; o <<= 1) {
                s += __shfl_xor(s, o, 64);
                ss += __shfl_xor(ss, o, 64);
            }
            float mu = s * (1.f / 256.f);
            float rs = rsqrtf(ss * (1.f / 256.f) - mu * mu + 1e-5f);
#pragma unroll
            for (int g4 = 0; g4 < 4; ++g4) {
                v[g4].x = (v[g4].x - mu) * rs;
                v[g4].y = (v[g4].y - mu) * rs;
                v[g4].z = (v[g4].z - mu) * rs;
                v[g4].w = (v[g4].w - mu) * rs;
            }
            if (l == 1) {
                float s2 = 0.f, ss2 = 0.f;
#pragma unroll
                for (int g4 = 0; g4 < 4; ++g4) {
                    float4 w4 = *(const float4*)&a.aw[c0 + (g4 << 2)];
                    float4 b4 = *(const float4*)&a.ab[c0 + (g4 << 2)];
                    v[g4].x = v[g4].x * w4.x + b4.x;
                    v[g4].y = v[g4].y * w4.y + b4.y;
                    v[g4].z = v[g4].z * w4.z + b4.z;
                    v[g4].w = v[g4].w * w4.w + b4.w;
                    s2 += v[g4].x + v[g4].y + v[g4].z + v[g4].w;
                    ss2 += v[g4].x * v[g4].x + v[g4].y * v[g4].y +
                           v[g4].z * v[g4].z + v[g4].w * v[g4].w;
                }
#pragma unroll
                for (int o = 1; o < 16; o <<= 1) {
                    s2 += __shfl_xor(s2, o, 64);
                    ss2 += __shfl_xor(ss2, o, 64);
                }
                float mu2 = s2 * (1.f / 256.f);
                float rs2 = rsqrtf(ss2 * (1.f / 256.f) - mu2 * mu2 + 1e-5f);
#pragma unroll
                for (int g4 = 0; g4 < 4; ++g4) {
                    v[g4].x = (v[g4].x - mu2) * rs2;
                    v[g4].y = (v[g4].y - mu2) * rs2;
                    v[g4].z = (v[g4].z - mu2) * rs2;
                    v[g4].w = (v[g4].w - mu2) * rs2;
                }
            }
#pragma unroll
            for (int g4 = 0; g4 < 4; ++g4) {
                short4v o;
                o[0] = (short)f2bf(v[g4].x);
                o[1] = (short)f2bf(v[g4].y);
                o[2] = (short)f2bf(v[g4].z);
                o[3] = (short)f2bf(v[g4].w);
                *(short4v*)&XH[r16][c0 + (g4 << 2)] = o;
            }
        }
        lbar();

        // ---------------- Q: QR = XH @ Wq'^T + qb
        // (attention K/V preloads issued here, hidden under the Q MFMAs)
        short8 kb[4], vfrag[2][2];
        {
            const unsigned short* Kt = a.Ktb[l];
            const unsigned short* Vt = a.Vtb[l];
            int h = wv;
#pragma unroll
            for (int nt = 0; nt < 4; ++nt)
                kb[nt] = *(const short8*)(
                    Kt + (size_t)((wl << 5) + (nt << 4) + l16) * 256 +
                    (h << 5) + (quad << 3));
#pragma unroll
            for (int ks = 0; ks < 2; ++ks)
#pragma unroll
                for (int dt = 0; dt < 2; ++dt)
                    vfrag[ks][dt] = *(const short8*)(
                        Vt + (size_t)((h << 5) + (dt << 4) + l16) * M_DIM +
                        (wl << 5) + (ks << 5) + (quad << 3));
        }
        {
            floatx4 acc[2][2];
            ZACC(acc);
            mfma32t((const short*)XH, 264, Pq, l16, quad, acc);
            const float* qb = a.qb[l];
#pragma unroll
            for (int ni = 0; ni < 2; ++ni) {
                int col = colw + (ni << 4) + l16;
                float bv = qb[col];
#pragma unroll
                for (int mi = 0; mi < 2; ++mi)
#pragma unroll
                    for (int r = 0; r < 4; ++r)
                        QR[(mi << 4) + (quad << 2) + r][col] =
                            (short)f2bf(acc[mi][ni][r] + bv);
            }
        }
        // wave-private QR slice: intra-wave LDS ordering only
        asm volatile("s_waitcnt lgkmcnt(0)" ::: "memory");

        // ---------------- attention: one head per wave, in-wave softmax
        BPre Pp;
        {
            int h = wv;
            short8 aq0 = *(const short8*)&QR[l16][(h << 5) + (quad << 3)];
            short8 aq1 = *(const short8*)&QR[16 + l16][(h << 5) + (quad << 3)];
            floatx4 c[2][4];
#pragma unroll
            for (int nt = 0; nt < 4; ++nt) {
                floatx4 z = {0.f, 0.f, 0.f, 0.f};
                c[0][nt] = __builtin_amdgcn_mfma_f32_16x16x32_bf16(aq0, kb[nt], z, 0, 0, 0);
                c[1][nt] = __builtin_amdgcn_mfma_f32_16x16x32_bf16(aq1, kb[nt], z, 0, 0, 0);
            }
            floatx4 ri[2];
#pragma unroll
            for (int m = 0; m < 2; ++m) {
#pragma unroll
                for (int nt = 0; nt < 4; ++nt) {
                    floatx4 e;
#pragma unroll
                    for (int r = 0; r < 4; ++r)
                        e[r] = __expf(c[m][nt][r] * ATT_SCALE);
                    c[m][nt] = e;
                }
                floatx4 s4 = c[m][0] + c[m][1] + c[m][2] + c[m][3];
#pragma unroll
                for (int r = 0; r < 4; ++r) {
                    float s = s4[r];
                    s += __shfl_xor(s, 1, 64);
                    s += __shfl_xor(s, 2, 64);
                    s += __shfl_xor(s, 4, 64);
                    s += __shfl_xor(s, 8, 64);
                    ri[m][r] = 1.f / s;
                }
            }
#pragma unroll
            for (int m = 0; m < 2; ++m)
#pragma unroll
                for (int nt = 0; nt < 4; ++nt)
#pragma unroll
                    for (int r = 0; r < 4; ++r)
                        PB[wv][(m << 4) + (quad << 2) + r][(nt << 4) + l16] =
                            (short)f2bf(c[m][nt][r] * ri[m][r]);
            asm volatile("s_waitcnt lgkmcnt(0)" ::: "memory");
            // proj B preload hidden under PV (R4 placement)
            preloadB(a.Wp[l], 256, 0, colw, l16, quad, Pp);
            floatx4 o[2][2];
#pragma unroll
            for (int m = 0; m < 2; ++m)
#pragma unroll
                for (int dt = 0; dt < 2; ++dt)
                    o[m][dt] = (floatx4){0.f, 0.f, 0.f, 0.f};
#pragma unroll
            for (int ks = 0; ks < 2; ++ks) {
                short8 pa0 =
                    *(const short8*)&PB[wv][l16][(ks << 5) + (quad << 3)];
                short8 pa1 =
                    *(const short8*)&PB[wv][16 + l16][(ks << 5) + (quad << 3)];
#pragma unroll
                for (int dt = 0; dt < 2; ++dt) {
                    o[0][dt] = __builtin_amdgcn_mfma_f32_16x16x32_bf16(
                        pa0, vfrag[ks][dt], o[0][dt], 0, 0, 0);
                    o[1][dt] = __builtin_amdgcn_mfma_f32_16x16x32_bf16(
                        pa1, vfrag[ks][dt], o[1][dt], 0, 0, 0);
                }
            }
            int h5 = wv << 5;
#pragma unroll
            for (int m = 0; m < 2; ++m)
#pragma unroll
                for (int dt = 0; dt < 2; ++dt)
#pragma unroll
                    for (int r = 0; r < 4; ++r)
                        AR[(m << 4) + (quad << 2) + r]
                          [h5 + (dt << 4) + l16] = (short)f2bf(o[m][dt][r]);
        }
        lbar();

        // ---------------- proj: Zf = AR @ Wp'^T + bproj (fp32)
        {
            floatx4 acc[2][2];
            ZACC(acc);
            mfma32t((const short*)AR, 264, Pp, l16, quad, acc);
            const float* bpj = a.bpj[l];
#pragma unroll
            for (int ni = 0; ni < 2; ++ni) {
                int col = colw + (ni << 4) + l16;
                float bv = bpj[col];
#pragma unroll
                for (int mi = 0; mi < 2; ++mi)
#pragma unroll
                    for (int r = 0; r < 4; ++r)
                        Zf[(mi << 4) + (quad << 2) + r][col] = acc[mi][ni][r] + bv;
            }
        }
        lbar();

        // ---------------- LNz: ZH = bf16(LN(Z)); Zf <- LN(Z)*pw+pb
        BPre Pm1a;
        preloadB(a.Wm1[l], 256, 0, colw, l16, quad, Pm1a);  // in flight
        {
            const float* pw = a.pw[l];
            const float* pb = a.pb[l];
            float4 v[4];
#pragma unroll
            for (int g4 = 0; g4 < 4; ++g4)
                v[g4] = *(const float4*)&Zf[r16][c0 + (g4 << 2)];
            float s = 0.f, ss = 0.f;
#pragma unroll
            for (int g4 = 0; g4 < 4; ++g4) {
                s += v[g4].x + v[g4].y + v[g4].z + v[g4].w;
                ss += v[g4].x * v[g4].x + v[g4].y * v[g4].y + v[g4].z * v[g4].z +
                      v[g4].w * v[g4].w;
            }
#pragma unroll
            for (int o = 1; o < 16; o <<= 1) {
                s += __shfl_xor(s, o, 64);
                ss += __shfl_xor(ss, o, 64);
            }
            float mu = s * (1.f / 256.f);
            float rs = rsqrtf(ss * (1.f / 256.f) - mu * mu + 1e-5f);
#pragma unroll
            for (int g4 = 0; g4 < 4; ++g4) {
                float4 z;
                z.x = (v[g4].x - mu) * rs;
                z.y = (v[g4].y - mu) * rs;
                z.z = (v[g4].z - mu) * rs;
                z.w = (v[g4].w - mu) * rs;
                short4v o;
                o[0] = (short)f2bf(z.x);
                o[1] = (short)f2bf(z.y);
                o[2] = (short)f2bf(z.z);
                o[3] = (short)f2bf(z.w);
                *(short4v*)&ZH[r16][c0 + (g4 << 2)] = o;
                float4 w4 = *(const float4*)&pw[c0 + (g4 << 2)];
                float4 b4 = *(const float4*)&pb[c0 + (g4 << 2)];
                float4 za;
                za.x = z.x * w4.x + b4.x;
                za.y = z.y * w4.y + b4.y;
                za.z = z.z * w4.z + b4.z;
                za.w = z.w * w4.w + b4.w;
                *(float4*)&Zf[r16][c0 + (g4 << 2)] = za;
            }
        }
        lbar();

        // ---------------- m1: gelu(ZH @ Wm1'^T + m1b) -> HH0(XH), HH1(QR)
        const float* m1b = a.m1b[l];
        BPre Pm2a;
        {
            floatx4 acc[2][2];
            ZACC(acc);
            mfma32t((const short*)ZH, 264, Pm1a, l16, quad, acc);
            BPre Pm1b;
            preloadB(a.Wm1[l] + (size_t)256 * 256, 256, 0, colw, l16, quad, Pm1b);
#pragma unroll
            for (int ni = 0; ni < 2; ++ni) {
                int col = colw + (ni << 4) + l16;
                float bv = m1b[col];
#pragma unroll
                for (int mi = 0; mi < 2; ++mi)
#pragma unroll
                    for (int r = 0; r < 4; ++r)
                        XH[(mi << 4) + (quad << 2) + r][col] =
                            (short)f2bf(gelu_exact(acc[mi][ni][r] + bv));
            }
            floatx4 acc2[2][2];
            ZACC(acc2);
            mfma32t((const short*)ZH, 264, Pm1b, l16, quad, acc2);
            preloadB(a.Wm2[l], 512, 0, colw, l16, quad, Pm2a);
#pragma unroll
            for (int ni = 0; ni < 2; ++ni) {
                int col = colw + (ni << 4) + l16;
                float bv = m1b[256 + col];
#pragma unroll
                for (int mi = 0; mi < 2; ++mi)
#pragma unroll
                    for (int r = 0; r < 4; ++r)
                        QR[(mi << 4) + (quad << 2) + r][col] =
                            (short)f2bf(gelu_exact(acc2[mi][ni][r] + bv));
            }
        }
        lbar();

        // ---------------- m2: x' = HH @ Wm2'^T + bm2 + Zf (K=512)
        {
            floatx4 macc[2][2];
            ZACC(macc);
            mfma32t((const short*)XH, 264, Pm2a, l16, quad, macc);
            BPre Pm2b;
            preloadB(a.Wm2[l], 512, 256, colw, l16, quad, Pm2b);
            mfma32t((const short*)QR, 264, Pm2b, l16, quad, macc);
            const float* b2 = a.bm2v[l];
#pragma unroll
            for (int ni = 0; ni < 2; ++ni) {
                int col = colw + (ni << 4) + l16;
                float bv = b2[col];
#pragma unroll
                for (int mi = 0; mi < 2; ++mi)
#pragma unroll
                    for (int r = 0; r < 4; ++r) {
                        int row = (mi << 4) + (quad << 2) + r;
                        Zf[row][col] = macc[mi][ni][r] + bv + Zf[row][col];
                    }
            }
        }
        lbar();
    }

    // ---------------- folded out: LN_post1 + channel-L2-norm + store -------
    {
        float4 v[4];
#pragma unroll
        for (int g4 = 0; g4 < 4; ++g4)
            v[g4] = *(const float4*)&Zf[r16][c0 + (g4 << 2)];
        float s = 0.f, ss = 0.f;
#pragma unroll
        for (int g4 = 0; g4 < 4; ++g4) {
            s += v[g4].x + v[g4].y + v[g4].z + v[g4].w;
            ss += v[g4].x * v[g4].x + v[g4].y * v[g4].y + v[g4].z * v[g4].z +
                  v[g4].w * v[g4].w;
        }
#pragma unroll
        for (int o = 1; o < 16; o <<= 1) {
            s += __shfl_xor(s, o, 64);
            ss += __shfl_xor(ss, o, 64);
        }
        float mu = s * (1.f / 256.f);
        float rs = rsqrtf(ss * (1.f / 256.f) - mu * mu + 1e-5f);
        float ss2 = 0.f;
#pragma unroll
        for (int g4 = 0; g4 < 4; ++g4) {
            float4 w4 = *(const float4*)&a.ow[c0 + (g4 << 2)];
            float4 b4 = *(const float4*)&a.ob[c0 + (g4 << 2)];
            v[g4].x = (v[g4].x - mu) * rs * w4.x + b4.x;
            v[g4].y = (v[g4].y - mu) * rs * w4.y + b4.y;
            v[g4].z = (v[g4].z - mu) * rs * w4.z + b4.z;
            v[g4].w = (v[g4].w - mu) * rs * w4.w + b4.w;
            ss2 += v[g4].x * v[g4].x + v[g4].y * v[g4].y + v[g4].z * v[g4].z +
                   v[g4].w * v[g4].w;
        }
#pragma unroll
        for (int o = 1; o < 16; o <<= 1) ss2 += __shfl_xor(ss2, o, 64);
        float sc = 1.f / fmaxf(sqrtf(ss2), 1e-12f);
        if (r16 < qcnt) {
            int m = gp[r16];
            float* op = a.oout + m;
#pragma unroll
            for (int g4 = 0; g4 < 4; ++g4) {
                int cb = c0 + (g4 << 2);
                op[(size_t)(cb + 0) * M_DIM] = v[g4].x * sc;
                op[(size_t)(cb + 1) * M_DIM] = v[g4].y * sc;
                op[(size_t)(cb + 2) * M_DIM] = v[g4].z * sc;
                op[(size_t)(cb + 3) * M_DIM] = v[g4].w * sc;
            }
        }
    }
}

// ---------------------------------------------------------------------------
extern "C" void kernel_launch(void* const* d_in, const int* in_sizes, int n_in,
                              void* d_out, int out_size, void* d_ws, size_t ws_size,
                              hipStream_t stream) {
    const float* grd2sat = (const float*)d_in[0];
    const float* grd_x   = (const float*)d_in[1];
    const float* u       = (const float*)d_in[2];
    const float* ln_q_w  = (const float*)d_in[3];
    const float* ln_q_b  = (const float*)d_in[4];
    const float* ln_k_w  = (const float*)d_in[5];
    const float* ln_k_b  = (const float*)d_in[6];
    const float* ln_v_w  = (const float*)d_in[7];
    const float* ln_v_b  = (const float*)d_in[8];
    const float* Wq      = (const float*)d_in[9];
    const float* Wk      = (const float*)d_in[10];
    const float* Wv      = (const float*)d_in[11];
    const float* Wproj   = (const float*)d_in[12];
    const float* bproj   = (const float*)d_in[13];
    const float* ln_pre_w = (const float*)d_in[14];
    const float* ln_pre_b = (const float*)d_in[15];
    const float* Wm1     = (const float*)d_in[16];
    const float* bm1     = (const float*)d_in[17];
    const float* Wm2     = (const float*)d_in[18];
    const float* bm2     = (const float*)d_in[19];
    const float* ln_post_w = (const float*)d_in[20];
    const float* ln_post_b = (const float*)d_in[21];

    float* ws   = (float*)d_ws;
    unsigned short* yhat = (unsigned short*)ws;  // 2 MB bf16
    float* xcur = ws + 1048576;              // 4 MB
    unsigned short* Ktab0 = (unsigned short*)(ws + 6291456); // 2 MB
    unsigned short* Vt0   = (unsigned short*)(ws + 6815744); // 2 MB
    unsigned short* Ktab1 = (unsigned short*)(ws + 7340032); // 2 MB
    unsigned short* Vt1   = (unsigned short*)(ws + 7864320); // 2 MB
    unsigned short* Bt    = (unsigned short*)(ws + 8388608); // 2 MB
    float* biasbuf = ws + 8912896;           // 2560 floats
    int*  perm    = (int*)(ws + 8915456);
    int4* chunks  = (int4*)(ws + 8919552);
    int*  nchunks = (int*)(ws + 8921600);
    const size_t BS = 524288;
    const size_t OQ = 0, OKV = 65536, OP = 196608, OM1 = 262144, OM2 = 393216;

    dim3 b256(256);

    PrepArgs pa;
    pa.grd2sat = grd2sat; pa.xcur = xcur;
    pa.grd_x = grd_x;     pa.yhat = yhat;
    pa.u = u; pa.perm = perm; pa.chunks = chunks; pa.nchunks = nchunks;
    {
        int base = 0;
        for (int i = 0; i < 2; ++i) {
            int e = 6 * i;
            unsigned short* bt = Bt + i * BS;
            pa.win[e+0] = Wq + i * 65536;    pa.wout[e+0] = bt + OQ;
            pa.wlnw[e+0] = ln_q_w + i * 256; pa.wR[e+0] = 256; pa.wC[e+0] = 256;
            pa.win[e+1] = Wk + i * 65536;    pa.wout[e+1] = bt + OKV;
            pa.wlnw[e+1] = ln_k_w + i * 256; pa.wR[e+1] = 256; pa.wC[e+1] = 256;
            pa.win[e+2] = Wv + i * 65536;    pa.wout[e+2] = bt + OKV + 65536;
            pa.wlnw[e+2] = ln_v_w + i * 256; pa.wR[e+2] = 256; pa.wC[e+2] = 256;
            pa.win[e+3] = Wproj + i * 65536; pa.wout[e+3] = bt + OP;
            pa.wlnw[e+3] = nullptr;          pa.wR[e+3] = 256; pa.wC[e+3] = 256;
            pa.win[e+4] = Wm1 + i * 131072;  pa.wout[e+4] = bt + OM1;
            pa.wlnw[e+4] = ln_pre_w + i * 256; pa.wR[e+4] = 256; pa.wC[e+4] = 512;
            pa.win[e+5] = Wm2 + i * 131072;  pa.wout[e+5] = bt + OM2;
            pa.wlnw[e+5] = nullptr;          pa.wR[e+5] = 512; pa.wC[e+5] = 256;
        }
        for (int e = 0; e < 12; ++e) {
            pa.wbase[e] = base;
            base += (pa.wR[e] >> 5) * (pa.wC[e] >> 5);
        }
        pa.wbase[12] = base;  // 1024
        for (int i = 0; i < 2; ++i) {
            int jb = 5 * i;
            float* bb = biasbuf + i * 1280;
            pa.fW[jb+0] = Wq + i * 65536; pa.flnb[jb+0] = ln_q_b + i * 256;
            pa.fbase[jb+0] = nullptr; pa.fout[jb+0] = bb;
            pa.fN[jb+0] = 256; pa.fwcol[jb+0] = 0; pa.focol[jb+0] = 0;
            pa.fW[jb+1] = Wk + i * 65536; pa.flnb[jb+1] = ln_k_b + i * 256;
            pa.fbase[jb+1] = nullptr; pa.fout[jb+1] = bb + 256;
            pa.fN[jb+1] = 256; pa.fwcol[jb+1] = 0; pa.focol[jb+1] = 0;
            pa.fW[jb+2] = Wv + i * 65536; pa.flnb[jb+2] = ln_v_b + i * 256;
            pa.fbase[jb+2] = nullptr; pa.fout[jb+2] = bb + 256;
            pa.fN[jb+2] = 256; pa.fwcol[jb+2] = 0; pa.focol[jb+2] = 256;
            pa.fW[jb+3] = Wm1 + i * 131072; pa.flnb[jb+3] = ln_pre_b + i * 256;
            pa.fbase[jb+3] = bm1 + i * 512; pa.fout[jb+3] = bb + 768;
            pa.fN[jb+3] = 512; pa.fwcol[jb+3] = 0; pa.focol[jb+3] = 0;
            pa.fW[jb+4] = Wm1 + i * 131072; pa.flnb[jb+4] = ln_pre_b + i * 256;
            pa.fbase[jb+4] = bm1 + i * 512; pa.fout[jb+4] = bb + 768;
            pa.fN[jb+4] = 512; pa.fwcol[jb+4] = 256; pa.focol[jb+4] = 256;
        }
    }
    prep_kernel<<<681, b256, 0, stream>>>(pa);

    // ---- K/V tables for both transformer blocks
    GJ jkv0 = {};
    jkv0.A = yhat; jkv0.Bt = Bt + OKV; jkv0.bias = biasbuf + 256;
    jkv0.out = Ktab0; jkv0.out2 = Vt0; jkv0.K = 256; jkv0.N = 512;
    GJ jkv1 = {};
    jkv1.A = yhat; jkv1.Bt = Bt + BS + OKV; jkv1.bias = biasbuf + 1280 + 256;
    jkv1.out = Ktab1; jkv1.out2 = Vt1; jkv1.K = 256; jkv1.N = 512;
    kv_kernel<<<dim3(128, 4), b256, 0, stream>>>(jkv0, jkv1);

    // ---- mega chunk kernel v12 (R15-exact schedule)
    MegaArgs ma;
    ma.xcur = xcur; ma.perm = perm; ma.chunks = chunks; ma.nchunks = nchunks;
    for (int i = 0; i < 2; ++i) {
        const unsigned short* bt = Bt + i * BS;
        ma.Wq[i] = bt + OQ; ma.Wp[i] = bt + OP;
        ma.Wm1[i] = bt + OM1; ma.Wm2[i] = bt + OM2;
        ma.Ktb[i] = i ? Ktab1 : Ktab0; ma.Vtb[i] = i ? Vt1 : Vt0;
        ma.qb[i] = biasbuf + i * 1280;
        ma.m1b[i] = biasbuf + i * 1280 + 768;
        ma.bpj[i] = bproj + i * 256;
        ma.bm2v[i] = bm2 + i * 256;
        ma.pw[i] = ln_pre_w + i * 256;
        ma.pb[i] = ln_pre_b + i * 256;
    }
    ma.aw = ln_post_w; ma.ab = ln_post_b;         // block-0 ln_post (LN2)
    ma.ow = ln_post_w + 256; ma.ob = ln_post_b + 256;  // block-1 ln_post (out)
    ma.oout = (float*)d_out;
    mega_kernel<<<288, dim3(512), 0, stream>>>(ma);
}